// Round 4
// baseline (111.332 us; speedup 1.0000x reference)
//
#include <hip/hip_runtime.h>
#include <hip/hip_bf16.h>

// DoyleSDE derivative: elementwise over rows of x (B,4), fp32.
// Memory-bound streaming: 16B/row in, 16B/row out. Unroll x4 + nontemporal.

#define C_AS  0.01016f
#define C_VS  0.65f
#define C_AP  0.0361f
#define C_VP  0.1408f
#define R_P   0.5f
#define R_S0  6.5f
#define A_RS  18.0f
#define V_TOT 5.058f
#define V_TO2 6.0f
#define O_2A  0.2f
#define M_0   0.36f
#define C_L   0.03f
#define C_R   0.05f

typedef float f32x4 __attribute__((ext_vector_type(4)));

__device__ __forceinline__ f32x4 doyle_row(f32x4 v, float k0, float k1,
                                           float k2, float k3, float cb) {
    const float inv_cvp  = 1.0f / C_VP;
    const float inv_cas  = 1.0f / C_AS;
    const float inv_cvs  = 1.0f / C_VS;
    const float inv_cap  = 1.0f / C_AP;
    const float inv_rp   = 1.0f / R_P;
    const float inv_vto2 = 1.0f / V_TO2;

    const float Pas = v.x, Pvs = v.y, Pap = v.z, O2v = v.w;
    const float Vvp = V_TOT - (C_AS * Pas + C_VS * Pvs + C_AP * Pap);
    const float Pvp = Vvp * inv_cvp;
    const float Rs  = A_RS * O2v + R_S0;
    const float Fs  = (Pas - Pvs) / Rs;
    const float Fp  = (Pap - Pvp) * inv_rp;
    const float dO2 = O_2A - O2v;
    const float H   = cb - (Pas * k0 + Pvs * k1 + Pap * k2 + O2v * k3);

    f32x4 r;
    r.x = (C_L * H * Pvp - Fs) * inv_cas;
    r.y = (Fs - C_R * H * Pvs) * inv_cvs;
    r.z = (C_R * H * Pvs - Fp) * inv_cap;
    r.w = (Fs * dO2 - M_0) * inv_vto2;
    return r;
}

__global__ __launch_bounds__(256) void doyle_kernel(
    const f32x4* __restrict__ x,
    const float* __restrict__ K,
    const float* __restrict__ bias,
    f32x4* __restrict__ out,
    int n)
{
    const float k0 = K[0], k1 = K[1], k2 = K[2], k3 = K[3];
    const float cb = bias[0];

    const int tid    = blockIdx.x * blockDim.x + threadIdx.x;
    const int stride = gridDim.x * blockDim.x;
    const int stride4 = 4 * stride;

    int i = tid;
    // Unroll x4: four independent 16B NT loads in flight per iteration.
    for (; i + 3 * stride < n; i += stride4) {
        const f32x4 v0 = __builtin_nontemporal_load(&x[i]);
        const f32x4 v1 = __builtin_nontemporal_load(&x[i + stride]);
        const f32x4 v2 = __builtin_nontemporal_load(&x[i + 2 * stride]);
        const f32x4 v3 = __builtin_nontemporal_load(&x[i + 3 * stride]);
        const f32x4 r0 = doyle_row(v0, k0, k1, k2, k3, cb);
        const f32x4 r1 = doyle_row(v1, k0, k1, k2, k3, cb);
        const f32x4 r2 = doyle_row(v2, k0, k1, k2, k3, cb);
        const f32x4 r3 = doyle_row(v3, k0, k1, k2, k3, cb);
        __builtin_nontemporal_store(r0, &out[i]);
        __builtin_nontemporal_store(r1, &out[i + stride]);
        __builtin_nontemporal_store(r2, &out[i + 2 * stride]);
        __builtin_nontemporal_store(r3, &out[i + 3 * stride]);
    }
    for (; i < n; i += stride) {
        const f32x4 v0 = __builtin_nontemporal_load(&x[i]);
        const f32x4 r0 = doyle_row(v0, k0, k1, k2, k3, cb);
        __builtin_nontemporal_store(r0, &out[i]);
    }
}

extern "C" void kernel_launch(void* const* d_in, const int* in_sizes, int n_in,
                              void* d_out, int out_size, void* d_ws, size_t ws_size,
                              hipStream_t stream) {
    // Inputs (setup_inputs order): t(1), x(B*4), K(4), controlBias(1)
    const f32x4* x   = (const f32x4*)d_in[1];
    const float* K   = (const float*)d_in[2];
    const float* cb  = (const float*)d_in[3];
    f32x4* out = (f32x4*)d_out;

    const int n = in_sizes[1] / 4;  // number of rows

    const int block = 256;
    int grid = (n + block - 1) / block;
    if (grid > 2048) grid = 2048;

    doyle_kernel<<<grid, block, 0, stream>>>(x, K, cb, out, n);
}

// Round 5
// 95.230 us; speedup vs baseline: 1.1691x; 1.1691x over previous
//
#include <hip/hip_runtime.h>
#include <hip/hip_bf16.h>

// DoyleSDE derivative: elementwise over rows of x (B,4), fp32.
// Memory-bound streaming: 16B/row in, 16B/row out.
// Unroll x2 with block-contiguous 512-row chunks (two dense 1KB/wave loads
// 4KB apart) + nontemporal hints. Unroll x4 regressed (VGPR/occupancy).

#define C_AS  0.01016f
#define C_VS  0.65f
#define C_AP  0.0361f
#define C_VP  0.1408f
#define R_P   0.5f
#define R_S0  6.5f
#define A_RS  18.0f
#define V_TOT 5.058f
#define V_TO2 6.0f
#define O_2A  0.2f
#define M_0   0.36f
#define C_L   0.03f
#define C_R   0.05f

typedef float f32x4 __attribute__((ext_vector_type(4)));

__device__ __forceinline__ f32x4 doyle_row(f32x4 v, float k0, float k1,
                                           float k2, float k3, float cb) {
    const float inv_cvp  = 1.0f / C_VP;
    const float inv_cas  = 1.0f / C_AS;
    const float inv_cvs  = 1.0f / C_VS;
    const float inv_cap  = 1.0f / C_AP;
    const float inv_rp   = 1.0f / R_P;
    const float inv_vto2 = 1.0f / V_TO2;

    const float Pas = v.x, Pvs = v.y, Pap = v.z, O2v = v.w;
    const float Vvp = V_TOT - (C_AS * Pas + C_VS * Pvs + C_AP * Pap);
    const float Pvp = Vvp * inv_cvp;
    const float Rs  = A_RS * O2v + R_S0;
    const float Fs  = (Pas - Pvs) / Rs;
    const float Fp  = (Pap - Pvp) * inv_rp;
    const float dO2 = O_2A - O2v;
    const float H   = cb - (Pas * k0 + Pvs * k1 + Pap * k2 + O2v * k3);

    f32x4 r;
    r.x = (C_L * H * Pvp - Fs) * inv_cas;
    r.y = (Fs - C_R * H * Pvs) * inv_cvs;
    r.z = (C_R * H * Pvs - Fp) * inv_cap;
    r.w = (Fs * dO2 - M_0) * inv_vto2;
    return r;
}

__global__ __launch_bounds__(256) void doyle_kernel(
    const f32x4* __restrict__ x,
    const float* __restrict__ K,
    const float* __restrict__ bias,
    f32x4* __restrict__ out,
    int n)
{
    const float k0 = K[0], k1 = K[1], k2 = K[2], k3 = K[3];
    const float cb = bias[0];

    const int tid = threadIdx.x;

    // Block-contiguous chunks of 512 rows; grid-stride over chunks.
    // Thread t handles rows c*512+t and c*512+256+t.
    const int nchunks_full = n / 512;
    for (int c = blockIdx.x; c < nchunks_full; c += gridDim.x) {
        const int i0 = c * 512 + tid;
        const int i1 = i0 + 256;
        const f32x4 v0 = __builtin_nontemporal_load(&x[i0]);
        const f32x4 v1 = __builtin_nontemporal_load(&x[i1]);
        const f32x4 r0 = doyle_row(v0, k0, k1, k2, k3, cb);
        const f32x4 r1 = doyle_row(v1, k0, k1, k2, k3, cb);
        __builtin_nontemporal_store(r0, &out[i0]);
        __builtin_nontemporal_store(r1, &out[i1]);
    }

    // Tail (n not a multiple of 512): handled by the last grid pass.
    const int tail_base = nchunks_full * 512;
    if (tail_base < n) {
        for (int i = tail_base + blockIdx.x * 256 + tid; i < n;
             i += gridDim.x * 256) {
            const f32x4 v0 = __builtin_nontemporal_load(&x[i]);
            const f32x4 r0 = doyle_row(v0, k0, k1, k2, k3, cb);
            __builtin_nontemporal_store(r0, &out[i]);
        }
    }
}

extern "C" void kernel_launch(void* const* d_in, const int* in_sizes, int n_in,
                              void* d_out, int out_size, void* d_ws, size_t ws_size,
                              hipStream_t stream) {
    // Inputs (setup_inputs order): t(1), x(B*4), K(4), controlBias(1)
    const f32x4* x   = (const f32x4*)d_in[1];
    const float* K   = (const float*)d_in[2];
    const float* cb  = (const float*)d_in[3];
    f32x4* out = (f32x4*)d_out;

    const int n = in_sizes[1] / 4;  // number of rows

    const int block = 256;
    int grid = (n + 511) / 512;
    if (grid > 2048) grid = 2048;

    doyle_kernel<<<grid, block, 0, stream>>>(x, K, cb, out, n);
}